// Round 1
// baseline (761.575 us; speedup 1.0000x reference)
//
#include <hip/hip_runtime.h>

#define BN 1024
#define NV 6890
#define NJ 24
#define NBETA 10
#define PB 207            // pose basis = 9*(J-1)
#define N3 (NV*3)         // 20670

__device__ __constant__ int c_par[24] = {-1,0,0,0,1,2,3,4,5,6,7,8,9,9,9,12,13,14,16,17,18,19,20,21};

// ---------------------------------------------------------------------------
// K0: JS[j,c,l] = sum_v Jr[j,v]*shapedirs[v,c,l];  cj[j,c] = sum_v Jr[j,v]*vt[v,c]
// grid: 72 blocks (j*3+c), 256 threads
// ---------------------------------------------------------------------------
__global__ __launch_bounds__(256) void k_js(const float* __restrict__ Jr,
                                            const float* __restrict__ sd,
                                            const float* __restrict__ vtm,
                                            float* __restrict__ ws_js,
                                            float* __restrict__ ws_cj)
{
    int jc = blockIdx.x;            // 0..71
    int j = jc / 3, c = jc % 3;
    float acc[11];
    #pragma unroll
    for (int l = 0; l < 11; l++) acc[l] = 0.f;

    for (int v = threadIdx.x; v < NV; v += 256) {
        float r = Jr[j * NV + v];
        acc[10] += r * vtm[v * 3 + c];
        const float* s = sd + (size_t)(v * 3 + c) * NBETA;
        #pragma unroll
        for (int l = 0; l < NBETA; l++) acc[l] += r * s[l];
    }

    __shared__ float red[4][11];
    int lane = threadIdx.x & 63, wv = threadIdx.x >> 6;
    #pragma unroll
    for (int l = 0; l < 11; l++) {
        float x = acc[l];
        x += __shfl_down(x, 32, 64);
        x += __shfl_down(x, 16, 64);
        x += __shfl_down(x, 8, 64);
        x += __shfl_down(x, 4, 64);
        x += __shfl_down(x, 2, 64);
        x += __shfl_down(x, 1, 64);
        if (lane == 0) red[wv][l] = x;
    }
    __syncthreads();
    if (threadIdx.x == 0) {
        #pragma unroll
        for (int l = 0; l < 11; l++) {
            float s = red[0][l] + red[1][l] + red[2][l] + red[3][l];
            if (l < NBETA) ws_js[jc * NBETA + l] = s;
            else           ws_cj[jc] = s;
        }
    }
}

// ---------------------------------------------------------------------------
// K1: per-batch joints + kinematic chain. 4 batches/block, 16 lanes/batch.
// Writes A_rel (b,24,12) to ws and posed_joints to out tail.
// ---------------------------------------------------------------------------
__global__ __launch_bounds__(64) void k_chain(const float* __restrict__ betas,
                                              const float* __restrict__ grot,
                                              const float* __restrict__ bpose,
                                              const float* __restrict__ ws_js,
                                              const float* __restrict__ ws_cj,
                                              float* __restrict__ ws_arel,
                                              float* __restrict__ pj)   // out + BN*NV*3
{
    int lb = threadIdx.x >> 4;      // 0..3
    int e  = threadIdx.x & 15;      // 0..15
    int b  = blockIdx.x * 4 + lb;

    __shared__ float jt[4][72];
    __shared__ float tl[4][288];
    __shared__ float a[4][288];

    // Jt[j,c] = cj + JS @ betas[b]
    for (int idx = e; idx < 72; idx += 16) {
        float acc = ws_cj[idx];
        const float* jsrow = ws_js + idx * NBETA;
        const float* be = betas + b * NBETA;
        #pragma unroll
        for (int l = 0; l < NBETA; l++) acc += be[l] * jsrow[l];
        jt[lb][idx] = acc;
    }
    __syncthreads();

    // T_local (3x4 per joint)
    for (int idx = e; idx < 288; idx += 16) {
        int j = idx / 12, e12 = idx % 12, m = e12 >> 2, n = e12 & 3;
        float val;
        if (n < 3) {
            val = (j == 0) ? grot[(size_t)b * 9 + m * 3 + n]
                           : bpose[((size_t)b * 23 + (j - 1)) * 9 + m * 3 + n];
        } else {
            val = jt[lb][j * 3 + m];
            if (j > 0) val -= jt[lb][c_par[j] * 3 + m];
        }
        tl[lb][idx] = val;
    }
    __syncthreads();

    if (e < 12) a[lb][e] = tl[lb][e];
    for (int i = 1; i < 24; i++) {
        __syncthreads();
        if (e < 12) {
            int p = c_par[i];
            int m = e >> 2, n = e & 3;
            float val = a[lb][p*12 + m*4 + 0] * tl[lb][i*12 + 0 + n]
                      + a[lb][p*12 + m*4 + 1] * tl[lb][i*12 + 4 + n]
                      + a[lb][p*12 + m*4 + 2] * tl[lb][i*12 + 8 + n];
            if (n == 3) val += a[lb][p*12 + m*4 + 3];
            a[lb][i*12 + e] = val;
        }
    }
    __syncthreads();

    // posed joints
    for (int idx = e; idx < 72; idx += 16) {
        int j = idx / 3, m = idx % 3;
        pj[(size_t)b * 72 + idx] = a[lb][j*12 + m*4 + 3];
    }
    // A_rel: rotation kept, translation -> t - R @ Jt[j]
    for (int idx = e; idx < 288; idx += 16) {
        int j = idx / 12, e12 = idx % 12, m = e12 >> 2, n = e12 & 3;
        float val;
        if (n < 3) {
            val = a[lb][idx];
        } else {
            val = a[lb][j*12 + m*4 + 3]
                - a[lb][j*12 + m*4 + 0] * jt[lb][j*3 + 0]
                - a[lb][j*12 + m*4 + 1] * jt[lb][j*3 + 1]
                - a[lb][j*12 + m*4 + 2] * jt[lb][j*3 + 2];
        }
        ws_arel[(size_t)b * 288 + idx] = val;
    }
}

// ---------------------------------------------------------------------------
// K2: fused v_shaped + pose GEMM + LBS.
// Tile: 64 vertices x 32 batches, 256 threads (vi = tid&63, bq = tid>>6 handles
// 8 batches each). LDS ~56 KB.
// ---------------------------------------------------------------------------
#define BT 32
__global__ __launch_bounds__(256) void k_vert(const float* __restrict__ betas,
                                              const float* __restrict__ bpose,
                                              const float* __restrict__ vtm,
                                              const float* __restrict__ sd,
                                              const float* __restrict__ pd,
                                              const float* __restrict__ w,
                                              const float* __restrict__ ws_arel,
                                              float* __restrict__ out)
{
    int vb = blockIdx.x;            // 0..107
    int bb = blockIdx.y;            // 0..31
    int tid = threadIdx.x;
    int vi = tid & 63;
    int bq = tid >> 6;              // 0..3
    int v = vb * 64 + vi;
    bool vok = v < NV;

    __shared__ __align__(16) float l_big[BT * 288];   // phase1: pf[b][208]; phase2: arel[b][288]
    __shared__ float l_bet[BT * NBETA];
    __shared__ float l_w[64 * 25];
    __shared__ __align__(16) float l_s[16 * 192];

    // betas
    for (int e = tid; e < BT * NBETA; e += 256)
        l_bet[e] = betas[(size_t)(bb * BT) * NBETA + e];
    // pose_feature, padded stride 208 (k=207 zero)
    for (int e = tid; e < BT * 208; e += 256) {
        int b_ = e / 208, k = e % 208;
        float x = 0.f;
        if (k < PB) {
            x = bpose[(size_t)(bb * BT + b_) * PB + k];
            int k9 = k % 9;
            if (k9 == 0 || k9 == 4 || k9 == 8) x -= 1.f;
        }
        l_big[b_ * 208 + k] = x;
    }
    // lbs weights, padded stride 25
    for (int e = tid; e < 64 * 24; e += 256) {
        int vv = e / 24, j = e % 24;
        int gv = vb * 64 + vv;
        l_w[vv * 25 + j] = (gv < NV) ? w[(size_t)gv * 24 + j] : 0.f;
    }
    __syncthreads();

    // ---- pose GEMM: disp[i][c] = sum_k pf[b][k] * pd[k][v*3+c]
    float disp[8][3];
    #pragma unroll
    for (int i = 0; i < 8; i++) { disp[i][0] = 0; disp[i][1] = 0; disp[i][2] = 0; }

    for (int kc = 0; kc < 208; kc += 16) {
        __syncthreads();
        for (int e = tid; e < 16 * 192; e += 256) {
            int kk = e / 192, col = e % 192;
            int k = kc + kk, gcol = vb * 192 + col;
            l_s[e] = (k < PB && gcol < N3) ? pd[(size_t)k * N3 + gcol] : 0.f;
        }
        __syncthreads();
        #pragma unroll
        for (int k4 = 0; k4 < 16; k4 += 4) {
            float p[4][3];
            #pragma unroll
            for (int q = 0; q < 4; q++) {
                p[q][0] = l_s[(k4 + q) * 192 + vi * 3 + 0];
                p[q][1] = l_s[(k4 + q) * 192 + vi * 3 + 1];
                p[q][2] = l_s[(k4 + q) * 192 + vi * 3 + 2];
            }
            #pragma unroll
            for (int i = 0; i < 8; i++) {
                float4 f = *(const float4*)&l_big[(bq * 8 + i) * 208 + kc + k4];
                disp[i][0] += f.x * p[0][0]; disp[i][1] += f.x * p[0][1]; disp[i][2] += f.x * p[0][2];
                disp[i][0] += f.y * p[1][0]; disp[i][1] += f.y * p[1][1]; disp[i][2] += f.y * p[1][2];
                disp[i][0] += f.z * p[2][0]; disp[i][1] += f.z * p[2][1]; disp[i][2] += f.z * p[2][2];
                disp[i][0] += f.w * p[3][0]; disp[i][1] += f.w * p[3][1]; disp[i][2] += f.w * p[3][2];
            }
        }
    }

    // ---- v_posed = v_template + shapedirs@betas + disp
    float t0 = vok ? vtm[v * 3 + 0] : 0.f;
    float t1 = vok ? vtm[v * 3 + 1] : 0.f;
    float t2 = vok ? vtm[v * 3 + 2] : 0.f;
    float sreg[30];
    #pragma unroll
    for (int l = 0; l < 30; l++) sreg[l] = vok ? sd[(size_t)v * 30 + l] : 0.f;

    float vp[8][3];
    #pragma unroll
    for (int i = 0; i < 8; i++) {
        float a0 = t0, a1 = t1, a2 = t2;
        const float* be = &l_bet[(bq * 8 + i) * NBETA];
        #pragma unroll
        for (int l = 0; l < NBETA; l++) {
            float bl = be[l];
            a0 += bl * sreg[l];
            a1 += bl * sreg[10 + l];
            a2 += bl * sreg[20 + l];
        }
        vp[i][0] = a0 + disp[i][0];
        vp[i][1] = a1 + disp[i][1];
        vp[i][2] = a2 + disp[i][2];
    }

    // ---- reload l_big with A_rel for this batch tile
    __syncthreads();
    for (int e = tid; e < BT * 288; e += 256)
        l_big[e] = ws_arel[(size_t)(bb * BT) * 288 + e];
    __syncthreads();

    // ---- LBS: out = sum_j w[v,j] * (R_j @ vp + t_j)
    float oacc[8][3];
    #pragma unroll
    for (int i = 0; i < 8; i++) { oacc[i][0] = 0; oacc[i][1] = 0; oacc[i][2] = 0; }

    for (int j = 0; j < 24; j++) {
        float wj = l_w[vi * 25 + j];
        #pragma unroll
        for (int i = 0; i < 8; i++) {
            const float4* Ab = (const float4*)&l_big[(bq * 8 + i) * 288 + j * 12];
            float4 r0 = Ab[0], r1 = Ab[1], r2 = Ab[2];
            float x = vp[i][0], y = vp[i][1], z = vp[i][2];
            oacc[i][0] += wj * (r0.x * x + r0.y * y + r0.z * z + r0.w);
            oacc[i][1] += wj * (r1.x * x + r1.y * y + r1.z * z + r1.w);
            oacc[i][2] += wj * (r2.x * x + r2.y * y + r2.z * z + r2.w);
        }
    }

    if (vok) {
        #pragma unroll
        for (int i = 0; i < 8; i++) {
            size_t b = (size_t)(bb * BT + bq * 8 + i);
            size_t base = (b * NV + v) * 3;
            out[base + 0] = oacc[i][0];
            out[base + 1] = oacc[i][1];
            out[base + 2] = oacc[i][2];
        }
    }
}

// ---------------------------------------------------------------------------
extern "C" void kernel_launch(void* const* d_in, const int* in_sizes, int n_in,
                              void* d_out, int out_size, void* d_ws, size_t ws_size,
                              hipStream_t stream) {
    const float* betas = (const float*)d_in[0];
    const float* grot  = (const float*)d_in[1];
    const float* bpose = (const float*)d_in[2];
    const float* vtm   = (const float*)d_in[3];
    const float* sd    = (const float*)d_in[4];
    const float* pd    = (const float*)d_in[5];
    const float* Jr    = (const float*)d_in[6];
    const float* w     = (const float*)d_in[7];
    float* out = (float*)d_out;
    float* ws  = (float*)d_ws;

    float* ws_js   = ws;          // 720
    float* ws_cj   = ws + 720;    // 72
    float* ws_arel = ws + 792;    // 1024*288

    k_js<<<72, 256, 0, stream>>>(Jr, sd, vtm, ws_js, ws_cj);
    k_chain<<<BN / 4, 64, 0, stream>>>(betas, grot, bpose, ws_js, ws_cj, ws_arel,
                                       out + (size_t)BN * NV * 3);
    k_vert<<<dim3((NV + 63) / 64, BN / BT), 256, 0, stream>>>(betas, bpose, vtm, sd, pd, w,
                                                              ws_arel, out);
}

// Round 2
// 576.378 us; speedup vs baseline: 1.3213x; 1.3213x over previous
//
#include <hip/hip_runtime.h>

#define BN 1024
#define NV 6890
#define NJ 24
#define NBETA 10
#define PB 207            // pose basis = 9*(J-1)
#define N3 (NV*3)         // 20670
#define BT 32             // batches per k_vert block

typedef __bf16 bf16x8 __attribute__((ext_vector_type(8)));
typedef float  f32x4  __attribute__((ext_vector_type(4)));

__device__ __constant__ int c_par[24] = {-1,0,0,0,1,2,3,4,5,6,7,8,9,9,9,12,13,14,16,17,18,19,20,21};

__device__ inline unsigned short f2bf(float f) {
    unsigned u = __float_as_uint(f);
    u += 0x7fff + ((u >> 16) & 1);          // RNE
    return (unsigned short)(u >> 16);
}

// ---------------------------------------------------------------------------
// K0: JS[j,c,l] = sum_v Jr[j,v]*shapedirs[v,c,l];  cj[j,c] = sum_v Jr[j,v]*vt[v,c]
// grid: (72, 8) — 8 v-segments, atomicAdd merge. ws_js/ws_cj must be zeroed.
// ---------------------------------------------------------------------------
__global__ __launch_bounds__(256) void k_js(const float* __restrict__ Jr,
                                            const float* __restrict__ sd,
                                            const float* __restrict__ vtm,
                                            float* __restrict__ ws_js,
                                            float* __restrict__ ws_cj)
{
    int jc = blockIdx.x;            // 0..71
    int j = jc / 3, c = jc % 3;
    int v0 = blockIdx.y * 862;
    int v1 = v0 + 862; if (v1 > NV) v1 = NV;

    float acc[11];
    #pragma unroll
    for (int l = 0; l < 11; l++) acc[l] = 0.f;

    for (int v = v0 + threadIdx.x; v < v1; v += 256) {
        float r = Jr[j * NV + v];
        acc[10] += r * vtm[v * 3 + c];
        const float* s = sd + (size_t)(v * 3 + c) * NBETA;
        #pragma unroll
        for (int l = 0; l < NBETA; l++) acc[l] += r * s[l];
    }

    __shared__ float red[4][11];
    int lane = threadIdx.x & 63, wv = threadIdx.x >> 6;
    #pragma unroll
    for (int l = 0; l < 11; l++) {
        float x = acc[l];
        x += __shfl_down(x, 32, 64);
        x += __shfl_down(x, 16, 64);
        x += __shfl_down(x, 8, 64);
        x += __shfl_down(x, 4, 64);
        x += __shfl_down(x, 2, 64);
        x += __shfl_down(x, 1, 64);
        if (lane == 0) red[wv][l] = x;
    }
    __syncthreads();
    if (threadIdx.x == 0) {
        #pragma unroll
        for (int l = 0; l < 11; l++) {
            float s = red[0][l] + red[1][l] + red[2][l] + red[3][l];
            if (l < NBETA) atomicAdd(&ws_js[jc * NBETA + l], s);
            else           atomicAdd(&ws_cj[jc], s);
        }
    }
}

// ---------------------------------------------------------------------------
// K1: per-batch joints + kinematic chain. 4 batches/block, 16 lanes/batch.
// ---------------------------------------------------------------------------
__global__ __launch_bounds__(64) void k_chain(const float* __restrict__ betas,
                                              const float* __restrict__ grot,
                                              const float* __restrict__ bpose,
                                              const float* __restrict__ ws_js,
                                              const float* __restrict__ ws_cj,
                                              float* __restrict__ ws_arel,
                                              float* __restrict__ pj)
{
    int lb = threadIdx.x >> 4;      // 0..3
    int e  = threadIdx.x & 15;      // 0..15
    int b  = blockIdx.x * 4 + lb;

    __shared__ float jt[4][72];
    __shared__ float tl[4][288];
    __shared__ float a[4][288];

    for (int idx = e; idx < 72; idx += 16) {
        float acc = ws_cj[idx];
        const float* jsrow = ws_js + idx * NBETA;
        const float* be = betas + b * NBETA;
        #pragma unroll
        for (int l = 0; l < NBETA; l++) acc += be[l] * jsrow[l];
        jt[lb][idx] = acc;
    }
    __syncthreads();

    for (int idx = e; idx < 288; idx += 16) {
        int j = idx / 12, e12 = idx % 12, m = e12 >> 2, n = e12 & 3;
        float val;
        if (n < 3) {
            val = (j == 0) ? grot[(size_t)b * 9 + m * 3 + n]
                           : bpose[((size_t)b * 23 + (j - 1)) * 9 + m * 3 + n];
        } else {
            val = jt[lb][j * 3 + m];
            if (j > 0) val -= jt[lb][c_par[j] * 3 + m];
        }
        tl[lb][idx] = val;
    }
    __syncthreads();

    if (e < 12) a[lb][e] = tl[lb][e];
    for (int i = 1; i < 24; i++) {
        __syncthreads();
        if (e < 12) {
            int p = c_par[i];
            int m = e >> 2, n = e & 3;
            float val = a[lb][p*12 + m*4 + 0] * tl[lb][i*12 + 0 + n]
                      + a[lb][p*12 + m*4 + 1] * tl[lb][i*12 + 4 + n]
                      + a[lb][p*12 + m*4 + 2] * tl[lb][i*12 + 8 + n];
            if (n == 3) val += a[lb][p*12 + m*4 + 3];
            a[lb][i*12 + e] = val;
        }
    }
    __syncthreads();

    for (int idx = e; idx < 72; idx += 16) {
        int j = idx / 3, m = idx % 3;
        pj[(size_t)b * 72 + idx] = a[lb][j*12 + m*4 + 3];
    }
    for (int idx = e; idx < 288; idx += 16) {
        int j = idx / 12, e12 = idx % 12, m = e12 >> 2, n = e12 & 3;
        float val;
        if (n < 3) {
            val = a[lb][idx];
        } else {
            val = a[lb][j*12 + m*4 + 3]
                - a[lb][j*12 + m*4 + 0] * jt[lb][j*3 + 0]
                - a[lb][j*12 + m*4 + 1] * jt[lb][j*3 + 1]
                - a[lb][j*12 + m*4 + 2] * jt[lb][j*3 + 2];
        }
        ws_arel[(size_t)b * 288 + idx] = val;
    }
}

// ---------------------------------------------------------------------------
// K2: MFMA pose GEMM (bf16) + fp32 v_shaped + LBS with scalar A_rel loads.
// Tile: 32 batches x 64 vertices (192 cols). 256 threads = 4 waves.
// GEMM: M=32 (2 mtiles), N=192 (12 ntiles, 3 per wave), K=207 pad 224.
// LDS: pf[32][232]bf16 (14848) + pdT[192][40]bf16 (15360), overlaid by
//      disp[32][196]f32 (25088); + l_w 6400 + l_bet 1280  => ~38 KB, 4 blk/CU.
// ---------------------------------------------------------------------------
__global__ __launch_bounds__(256, 4) void k_vert(const float* __restrict__ betas,
                                                 const float* __restrict__ bpose,
                                                 const float* __restrict__ vtm,
                                                 const float* __restrict__ sd,
                                                 const float* __restrict__ pd,
                                                 const float* __restrict__ w,
                                                 const float* __restrict__ ws_arel,
                                                 float* __restrict__ out)
{
    const int vb = blockIdx.x;            // 0..107
    const int bb = blockIdx.y;            // 0..31
    const int tid = threadIdx.x;
    const int wv = tid >> 6;              // wave 0..3
    const int lane = tid & 63;

    __shared__ __align__(16) unsigned char smem[30464];
    unsigned short* pf_l  = (unsigned short*)smem;            // [32][232]
    unsigned short* pdT_l = (unsigned short*)(smem + 14848);  // [192][40]
    float*          disp_l = (float*)smem;                    // [32][196]
    __shared__ float l_w[64 * 25];
    __shared__ float l_bet[BT * NBETA];

    // ---- stage pose_feature as bf16, K padded 207->224, row stride 232
    for (int e = tid; e < BT * 224; e += 256) {
        int b_ = e / 224, k = e % 224;
        float x = 0.f;
        if (k < PB) {
            x = bpose[(size_t)(bb * BT + b_) * PB + k];
            int k9 = k % 9;
            if (k9 == 0 || k9 == 4 || k9 == 8) x -= 1.f;
        }
        pf_l[b_ * 232 + k] = f2bf(x);
    }
    for (int e = tid; e < BT * NBETA; e += 256)
        l_bet[e] = betas[(size_t)(bb * BT) * NBETA + e];
    for (int e = tid; e < 64 * 24; e += 256) {
        int vv = e / 24, j = e % 24;
        int gv = vb * 64 + vv;
        l_w[vv * 25 + j] = (gv < NV) ? w[(size_t)gv * 24 + j] : 0.f;
    }

    // ---- MFMA pose GEMM
    const int half8 = (lane >> 4) * 8;
    const int r16   = lane & 15;
    f32x4 acc[2][3];
    #pragma unroll
    for (int mt = 0; mt < 2; mt++)
        #pragma unroll
        for (int t = 0; t < 3; t++)
            acc[mt][t] = (f32x4){0.f, 0.f, 0.f, 0.f};

    for (int kc = 0; kc < 224; kc += 32) {
        __syncthreads();
        // stage pd chunk transposed: pdT[col][kk], bf16
        for (int e = tid; e < 32 * 192; e += 256) {
            int kk = e / 192, col = e % 192;
            int k = kc + kk, gcol = vb * 192 + col;
            float val = (k < PB && gcol < N3) ? pd[(size_t)k * N3 + gcol] : 0.f;
            pdT_l[col * 40 + kk] = f2bf(val);
        }
        __syncthreads();

        bf16x8 a0 = *(const bf16x8*)(pf_l + r16 * 232 + kc + half8);
        bf16x8 a1 = *(const bf16x8*)(pf_l + (16 + r16) * 232 + kc + half8);
        #pragma unroll
        for (int t = 0; t < 3; t++) {
            bf16x8 bv = *(const bf16x8*)(pdT_l + (wv * 48 + t * 16 + r16) * 40 + half8);
            acc[0][t] = __builtin_amdgcn_mfma_f32_16x16x32_bf16(a0, bv, acc[0][t], 0, 0, 0);
            acc[1][t] = __builtin_amdgcn_mfma_f32_16x16x32_bf16(a1, bv, acc[1][t], 0, 0, 0);
        }
    }

    // ---- scatter acc into disp_l (overlays pf/pdT)
    __syncthreads();
    #pragma unroll
    for (int mt = 0; mt < 2; mt++) {
        #pragma unroll
        for (int t = 0; t < 3; t++) {
            int col = wv * 48 + t * 16 + r16;
            int brow = mt * 16 + (lane >> 4) * 4;
            #pragma unroll
            for (int r = 0; r < 4; r++)
                disp_l[(brow + r) * 196 + col] = acc[mt][t][r];
        }
    }
    __syncthreads();

    // ---- v_posed = v_template + shapedirs@betas + disp
    const int vi = tid & 63;
    const int bq = tid >> 6;
    const int v = vb * 64 + vi;
    const bool vok = v < NV;

    float vp[8][3];
    #pragma unroll
    for (int c = 0; c < 3; c++) {
        float tc = vok ? vtm[v * 3 + c] : 0.f;
        float s[NBETA];
        #pragma unroll
        for (int l = 0; l < NBETA; l++)
            s[l] = vok ? sd[(size_t)v * 30 + c * 10 + l] : 0.f;
        #pragma unroll
        for (int i = 0; i < 8; i++) {
            float a = tc;
            const float* be = &l_bet[(bq * 8 + i) * NBETA];
            #pragma unroll
            for (int l = 0; l < NBETA; l++) a += be[l] * s[l];
            vp[i][c] = a + disp_l[(bq * 8 + i) * 196 + vi * 3 + c];
        }
    }

    // ---- LBS: A_rel via wave-uniform scalar loads
    int bqs = __builtin_amdgcn_readfirstlane(bq);
    const float* __restrict__ Abase = ws_arel + ((size_t)bb * BT + (size_t)bqs * 8) * 288;

    float o[8][3];
    #pragma unroll
    for (int i = 0; i < 8; i++) { o[i][0] = 0.f; o[i][1] = 0.f; o[i][2] = 0.f; }

    for (int j = 0; j < 24; j++) {
        float wj = l_w[vi * 25 + j];
        #pragma unroll
        for (int i = 0; i < 8; i++) {
            const float* __restrict__ A = Abase + i * 288 + j * 12;
            float x = vp[i][0], y = vp[i][1], z = vp[i][2];
            o[i][0] += wj * (A[0] * x + A[1] * y + A[2]  * z + A[3]);
            o[i][1] += wj * (A[4] * x + A[5] * y + A[6]  * z + A[7]);
            o[i][2] += wj * (A[8] * x + A[9] * y + A[10] * z + A[11]);
        }
    }

    if (vok) {
        #pragma unroll
        for (int i = 0; i < 8; i++) {
            size_t b = (size_t)(bb * BT + bq * 8 + i);
            size_t base = (b * NV + v) * 3;
            out[base + 0] = o[i][0];
            out[base + 1] = o[i][1];
            out[base + 2] = o[i][2];
        }
    }
}

// ---------------------------------------------------------------------------
extern "C" void kernel_launch(void* const* d_in, const int* in_sizes, int n_in,
                              void* d_out, int out_size, void* d_ws, size_t ws_size,
                              hipStream_t stream) {
    const float* betas = (const float*)d_in[0];
    const float* grot  = (const float*)d_in[1];
    const float* bpose = (const float*)d_in[2];
    const float* vtm   = (const float*)d_in[3];
    const float* sd    = (const float*)d_in[4];
    const float* pd    = (const float*)d_in[5];
    const float* Jr    = (const float*)d_in[6];
    const float* w     = (const float*)d_in[7];
    float* out = (float*)d_out;
    float* ws  = (float*)d_ws;

    float* ws_js   = ws;          // 720
    float* ws_cj   = ws + 720;    // 72
    float* ws_arel = ws + 792;    // 1024*288

    hipMemsetAsync(ws, 0, 792 * sizeof(float), stream);
    k_js<<<dim3(72, 8), 256, 0, stream>>>(Jr, sd, vtm, ws_js, ws_cj);
    k_chain<<<BN / 4, 64, 0, stream>>>(betas, grot, bpose, ws_js, ws_cj, ws_arel,
                                       out + (size_t)BN * NV * 3);
    k_vert<<<dim3((NV + 63) / 64, BN / BT), 256, 0, stream>>>(betas, bpose, vtm, sd, pd, w,
                                                              ws_arel, out);
}

// Round 3
// 328.466 us; speedup vs baseline: 2.3186x; 1.7548x over previous
//
#include <hip/hip_runtime.h>

#define BN 1024
#define NV 6890
#define NJ 24
#define NBETA 10
#define PB 207            // pose basis = 9*(J-1)
#define N3 20670          // NV*3
#define NCOL 20736        // 108*192 padded GEMM columns
#define NCHUNK 7          // K = 224 = 207 pose + 10 betas + 1 template + 6 zero
#define BT 32             // batches per k_vert block

typedef __bf16 bf16x8 __attribute__((ext_vector_type(8)));
typedef float  f32x4  __attribute__((ext_vector_type(4)));

__device__ __constant__ int c_par[24] = {-1,0,0,0,1,2,3,4,5,6,7,8,9,9,9,12,13,14,16,17,18,19,20,21};

__device__ inline unsigned short f2bf(float f) {
    unsigned u = __float_as_uint(f);
    u += 0x7fff + ((u >> 16) & 1);          // RNE
    return (unsigned short)(u >> 16);
}

__device__ inline void dma16(const void* g, void* l) {
    __builtin_amdgcn_global_load_lds(
        (const __attribute__((address_space(1))) unsigned int*)g,
        (__attribute__((address_space(3))) unsigned int*)l, 16, 0, 0);
}

// ---------------------------------------------------------------------------
// k_prep: blocks [0,567): build blocked bf16 pdT_g[kc][col][40] with
//   rows 0..206 = posedirs, 207..216 = shapedirs^T, 217 = v_template, rest 0.
// blocks [567,1143): J_regressor reductions -> ws_jsp partials (72 jc x 8 seg).
// ---------------------------------------------------------------------------
__global__ __launch_bounds__(256) void k_prep(const float* __restrict__ pd,
                                              const float* __restrict__ sd,
                                              const float* __restrict__ vtm,
                                              const float* __restrict__ Jr,
                                              unsigned short* __restrict__ ws_pdt,
                                              float* __restrict__ ws_jsp)
{
    int blk = blockIdx.x;
    if (blk < 567) {
        int t = blk * 256 + threadIdx.x;           // 0..145151
        int kc = t / NCOL;
        int col = t - kc * NCOL;
        bool cok = col < N3;
        unsigned short* dst = ws_pdt + (size_t)t * 40;
        #pragma unroll
        for (int kk = 0; kk < 32; kk++) {
            int gk = kc * 32 + kk;
            float val = 0.f;
            if (cok) {
                if (gk < PB)             val = pd[(size_t)gk * N3 + col];
                else if (gk < PB + 10)   val = sd[(size_t)col * NBETA + (gk - PB)];
                else if (gk == PB + 10)  val = vtm[col];
            }
            dst[kk] = f2bf(val);
        }
        #pragma unroll
        for (int kk = 32; kk < 40; kk++) dst[kk] = 0;
    } else {
        int b2 = blk - 567;            // 0..575
        int jc = b2 >> 3;              // 0..71
        int seg = b2 & 7;              // 0..7
        int j = jc / 3, c = jc % 3;
        int v0 = seg * 862;
        int v1 = v0 + 862; if (v1 > NV) v1 = NV;

        float acc[11];
        #pragma unroll
        for (int l = 0; l < 11; l++) acc[l] = 0.f;

        for (int v = v0 + threadIdx.x; v < v1; v += 256) {
            float r = Jr[j * NV + v];
            acc[10] += r * vtm[v * 3 + c];
            const float* s = sd + (size_t)(v * 3 + c) * NBETA;
            #pragma unroll
            for (int l = 0; l < NBETA; l++) acc[l] += r * s[l];
        }

        __shared__ float red[4][11];
        int lane = threadIdx.x & 63, wv = threadIdx.x >> 6;
        #pragma unroll
        for (int l = 0; l < 11; l++) {
            float x = acc[l];
            x += __shfl_down(x, 32, 64);
            x += __shfl_down(x, 16, 64);
            x += __shfl_down(x, 8, 64);
            x += __shfl_down(x, 4, 64);
            x += __shfl_down(x, 2, 64);
            x += __shfl_down(x, 1, 64);
            if (lane == 0) red[wv][l] = x;
        }
        __syncthreads();
        if (threadIdx.x == 0) {
            #pragma unroll
            for (int l = 0; l < 11; l++)
                ws_jsp[((size_t)seg * 72 + jc) * 11 + l]
                    = red[0][l] + red[1][l] + red[2][l] + red[3][l];
        }
    }
}

// ---------------------------------------------------------------------------
// k_chain: 64 blocks x 256 threads, 16 batches/block (16 lanes per batch).
// Sums js partials in LDS, then joints + kinematic chain + A_rel.
// ---------------------------------------------------------------------------
__global__ __launch_bounds__(256) void k_chain(const float* __restrict__ betas,
                                               const float* __restrict__ grot,
                                               const float* __restrict__ bpose,
                                               const float* __restrict__ ws_jsp,
                                               float* __restrict__ ws_arel,
                                               float* __restrict__ pj)
{
    __shared__ float js_s[72 * 11];
    __shared__ float jt[16][72];
    __shared__ float tl[16][288];
    __shared__ float am[16][288];
    int tid = threadIdx.x;

    for (int e = tid; e < 72 * 11; e += 256) {
        float s = 0.f;
        #pragma unroll
        for (int seg = 0; seg < 8; seg++)
            s += ws_jsp[((size_t)seg * 72) * 11 + e];
        js_s[e] = s;
    }
    __syncthreads();

    int lb = tid >> 4;              // 0..15
    int e  = tid & 15;              // 0..15
    int b  = blockIdx.x * 16 + lb;

    for (int idx = e; idx < 72; idx += 16) {
        float acc = js_s[idx * 11 + 10];
        const float* be = betas + b * NBETA;
        #pragma unroll
        for (int l = 0; l < NBETA; l++) acc += be[l] * js_s[idx * 11 + l];
        jt[lb][idx] = acc;
    }
    __syncthreads();

    for (int idx = e; idx < 288; idx += 16) {
        int j = idx / 12, e12 = idx % 12, m = e12 >> 2, n = e12 & 3;
        float val;
        if (n < 3) {
            val = (j == 0) ? grot[(size_t)b * 9 + m * 3 + n]
                           : bpose[((size_t)b * 23 + (j - 1)) * 9 + m * 3 + n];
        } else {
            val = jt[lb][j * 3 + m];
            if (j > 0) val -= jt[lb][c_par[j] * 3 + m];
        }
        tl[lb][idx] = val;
    }
    __syncthreads();

    if (e < 12) am[lb][e] = tl[lb][e];
    for (int i = 1; i < 24; i++) {
        __syncthreads();
        if (e < 12) {
            int p = c_par[i];
            int m = e >> 2, n = e & 3;
            float val = am[lb][p*12 + m*4 + 0] * tl[lb][i*12 + 0 + n]
                      + am[lb][p*12 + m*4 + 1] * tl[lb][i*12 + 4 + n]
                      + am[lb][p*12 + m*4 + 2] * tl[lb][i*12 + 8 + n];
            if (n == 3) val += am[lb][p*12 + m*4 + 3];
            am[lb][i*12 + e] = val;
        }
    }
    __syncthreads();

    for (int idx = e; idx < 72; idx += 16) {
        int j = idx / 3, m = idx % 3;
        pj[(size_t)b * 72 + idx] = am[lb][j*12 + m*4 + 3];
    }
    for (int idx = e; idx < 288; idx += 16) {
        int j = idx / 12, e12 = idx % 12, m = e12 >> 2, n = e12 & 3;
        float val;
        if (n < 3) {
            val = am[lb][idx];
        } else {
            val = am[lb][j*12 + m*4 + 3]
                - am[lb][j*12 + m*4 + 0] * jt[lb][j*3 + 0]
                - am[lb][j*12 + m*4 + 1] * jt[lb][j*3 + 1]
                - am[lb][j*12 + m*4 + 2] * jt[lb][j*3 + 2];
        }
        ws_arel[(size_t)b * 288 + idx] = val;
    }
}

// ---------------------------------------------------------------------------
// k_vert: phase 1 = MFMA GEMM (pf+betas+1) x (pd;sd;vt) -> v_posed (disp).
//         phase 2 = MFMA T = w @ A_rel per 4-batch subtile + VALU apply.
// Tile 64 v x 32 b. LDS 51008 B -> 3 blocks/CU.
// ---------------------------------------------------------------------------
__global__ __launch_bounds__(256, 3) void k_vert(const float* __restrict__ betas,
                                                 const float* __restrict__ bpose,
                                                 const float* __restrict__ w,
                                                 const unsigned short* __restrict__ ws_pdt,
                                                 const float* __restrict__ ws_arel,
                                                 float* __restrict__ out)
{
    const int vb = blockIdx.x;            // 0..107
    const int bb = blockIdx.y;            // 0..31
    const int tid = threadIdx.x;
    const int wv = tid >> 6;
    const int lane = tid & 63;
    const int r16 = lane & 15;
    const int half8 = (lane >> 4) * 8;

    __shared__ __align__(16) unsigned char smem[30208];
    unsigned short* pf_l  = (unsigned short*)smem;            // [32][232]
    unsigned short* pdT_l = (unsigned short*)(smem + 14848);  // [192][40]
    float*          disp_l = (float*)smem;                    // [32][196] (phase 2)
    unsigned short* ArT_l = (unsigned short*)(smem + 25088);  // [48][40]  (phase 2)
    __shared__ __align__(16) float T_l[64 * 49];
    __shared__ __align__(16) float out_l[4 * 196];
    __shared__ __align__(16) unsigned short w_l[64 * 40];

    // ---- stage pose_feature + betas + 1.0, bf16, row stride 232
    for (int e = tid; e < BT * 224; e += 256) {
        int b_ = e / 224, k = e - b_ * 224;
        float x;
        if (k < PB) {
            x = bpose[(size_t)(bb * BT + b_) * PB + k];
            int k9 = k % 9;
            if (k9 == 0 || k9 == 4 || k9 == 8) x -= 1.f;
        } else if (k < PB + 10) {
            x = betas[(bb * BT + b_) * NBETA + (k - PB)];
        } else if (k == PB + 10) {
            x = 1.f;
        } else {
            x = 0.f;
        }
        pf_l[b_ * 232 + k] = f2bf(x);
    }
    // ---- stage lbs weights bf16, [v][j] stride 40, j>=24 zero
    for (int e = tid; e < 64 * 32; e += 256) {
        int vv = e >> 5, j = e & 31;
        int gv = vb * 64 + vv;
        float val = (j < 24 && gv < NV) ? w[(size_t)gv * 24 + j] : 0.f;
        w_l[vv * 40 + j] = f2bf(val);
    }

    // ---- DMA chunk 0
    {
        const unsigned short* src = ws_pdt + ((size_t)0 * NCOL + (size_t)vb * 192) * 40;
        for (int i = wv; i < 15; i += 4)
            dma16((const char*)src + i * 1024 + lane * 16, (char*)pdT_l + i * 1024);
    }
    __syncthreads();

    f32x4 acc[2][3];
    #pragma unroll
    for (int mt = 0; mt < 2; mt++)
        #pragma unroll
        for (int t = 0; t < 3; t++)
            acc[mt][t] = (f32x4){0.f, 0.f, 0.f, 0.f};

    for (int kc = 0; kc < NCHUNK; kc++) {
        // prefetch fragments into registers
        bf16x8 a0 = *(const bf16x8*)(pf_l + r16 * 232 + kc * 32 + half8);
        bf16x8 a1 = *(const bf16x8*)(pf_l + (16 + r16) * 232 + kc * 32 + half8);
        bf16x8 b0 = *(const bf16x8*)(pdT_l + (wv * 48 + r16) * 40 + half8);
        bf16x8 b1 = *(const bf16x8*)(pdT_l + (wv * 48 + 16 + r16) * 40 + half8);
        bf16x8 b2 = *(const bf16x8*)(pdT_l + (wv * 48 + 32 + r16) * 40 + half8);
        __syncthreads();                      // all frag reads done
        if (kc < NCHUNK - 1) {
            const unsigned short* src = ws_pdt + ((size_t)(kc + 1) * NCOL + (size_t)vb * 192) * 40;
            for (int i = wv; i < 15; i += 4)
                dma16((const char*)src + i * 1024 + lane * 16, (char*)pdT_l + i * 1024);
        }
        acc[0][0] = __builtin_amdgcn_mfma_f32_16x16x32_bf16(a0, b0, acc[0][0], 0, 0, 0);
        acc[1][0] = __builtin_amdgcn_mfma_f32_16x16x32_bf16(a1, b0, acc[1][0], 0, 0, 0);
        acc[0][1] = __builtin_amdgcn_mfma_f32_16x16x32_bf16(a0, b1, acc[0][1], 0, 0, 0);
        acc[1][1] = __builtin_amdgcn_mfma_f32_16x16x32_bf16(a1, b1, acc[1][1], 0, 0, 0);
        acc[0][2] = __builtin_amdgcn_mfma_f32_16x16x32_bf16(a0, b2, acc[0][2], 0, 0, 0);
        acc[1][2] = __builtin_amdgcn_mfma_f32_16x16x32_bf16(a1, b2, acc[1][2], 0, 0, 0);
        if (kc < NCHUNK - 1) __syncthreads(); // DMA(kc+1) landed
    }

    // ---- write v_posed to disp_l (overlays pf/pdT; all reads already done)
    #pragma unroll
    for (int mt = 0; mt < 2; mt++) {
        #pragma unroll
        for (int t = 0; t < 3; t++) {
            int col = wv * 48 + t * 16 + r16;
            int brow = mt * 16 + (lane >> 4) * 4;
            #pragma unroll
            for (int r = 0; r < 4; r++)
                disp_l[(brow + r) * 196 + col] = acc[mt][t][r];
        }
    }
    __syncthreads();

    // ---- phase 2: per 4-batch subtile, T = w @ A_rel via MFMA, then apply
    bf16x8 aw = *(const bf16x8*)(w_l + (wv * 16 + r16) * 40 + half8);

    for (int sub = 0; sub < 8; sub++) {
        // stage A_rel transposed: ArT[col=(b_l,m,n)][j]
        for (int e = tid; e < 48 * 24; e += 256) {
            int col = e / 24, j = e - col * 24;
            int b_l = col / 12, mn = col - b_l * 12;
            float val = ws_arel[((size_t)(bb * BT + sub * 4 + b_l)) * 288 + j * 12 + mn];
            ArT_l[col * 40 + j] = f2bf(val);
        }
        __syncthreads();

        bf16x8 bA0 = *(const bf16x8*)(ArT_l + r16 * 40 + half8);
        bf16x8 bA1 = *(const bf16x8*)(ArT_l + (16 + r16) * 40 + half8);
        bf16x8 bA2 = *(const bf16x8*)(ArT_l + (32 + r16) * 40 + half8);
        f32x4 z = (f32x4){0.f, 0.f, 0.f, 0.f};
        f32x4 t0 = __builtin_amdgcn_mfma_f32_16x16x32_bf16(aw, bA0, z, 0, 0, 0);
        f32x4 t1 = __builtin_amdgcn_mfma_f32_16x16x32_bf16(aw, bA1, z, 0, 0, 0);
        f32x4 t2 = __builtin_amdgcn_mfma_f32_16x16x32_bf16(aw, bA2, z, 0, 0, 0);

        int vrow = wv * 16 + (lane >> 4) * 4;
        #pragma unroll
        for (int r = 0; r < 4; r++) {
            T_l[(vrow + r) * 49 + r16]      = t0[r];
            T_l[(vrow + r) * 49 + 16 + r16] = t1[r];
            T_l[(vrow + r) * 49 + 32 + r16] = t2[r];
        }
        __syncthreads();

        // epilogue: thread (vi=lane, b_l=wv) computes 3 outputs
        {
            const float* Tv = &T_l[lane * 49 + wv * 12];
            float x = disp_l[(sub * 4 + wv) * 196 + lane * 3 + 0];
            float y = disp_l[(sub * 4 + wv) * 196 + lane * 3 + 1];
            float zz = disp_l[(sub * 4 + wv) * 196 + lane * 3 + 2];
            #pragma unroll
            for (int m = 0; m < 3; m++)
                out_l[wv * 196 + lane * 3 + m] =
                    Tv[m*4+0] * x + Tv[m*4+1] * y + Tv[m*4+2] * zz + Tv[m*4+3];
        }
        __syncthreads();

        // coalesced flush
        for (int e = tid; e < 4 * 192; e += 256) {
            int b_l = e / 192, idx = e - b_l * 192;
            int vglob = vb * 64 + idx / 3;
            if (vglob < NV)
                out[((size_t)(bb * BT + sub * 4 + b_l)) * N3 + (size_t)vb * 192 + idx]
                    = out_l[b_l * 196 + idx];
        }
        __syncthreads();
    }
}

// ---------------------------------------------------------------------------
extern "C" void kernel_launch(void* const* d_in, const int* in_sizes, int n_in,
                              void* d_out, int out_size, void* d_ws, size_t ws_size,
                              hipStream_t stream) {
    const float* betas = (const float*)d_in[0];
    const float* grot  = (const float*)d_in[1];
    const float* bpose = (const float*)d_in[2];
    const float* vtm   = (const float*)d_in[3];
    const float* sd    = (const float*)d_in[4];
    const float* pd    = (const float*)d_in[5];
    const float* Jr    = (const float*)d_in[6];
    const float* w     = (const float*)d_in[7];
    float* out = (float*)d_out;

    unsigned short* ws_pdt = (unsigned short*)d_ws;                 // 7*20736*40 u16 = 11.6 MB
    float* ws_arel = (float*)((char*)d_ws + (size_t)NCHUNK * NCOL * 40 * 2);  // 1024*288 f32
    float* ws_jsp  = ws_arel + (size_t)BN * 288;                    // 8*72*11 f32

    k_prep<<<567 + 576, 256, 0, stream>>>(pd, sd, vtm, Jr, ws_pdt, ws_jsp);
    k_chain<<<BN / 16, 256, 0, stream>>>(betas, grot, bpose, ws_jsp, ws_arel,
                                         out + (size_t)BN * N3);
    k_vert<<<dim3(108, BN / BT), 256, 0, stream>>>(betas, bpose, w, ws_pdt, ws_arel, out);
}

// Round 4
// 188.054 us; speedup vs baseline: 4.0498x; 1.7467x over previous
//
#include <hip/hip_runtime.h>

#define BN 1024
#define NV 6890
#define NBETA 10
#define PB 207            // pose basis = 9*(J-1)
#define N3 20670          // NV*3
#define NCOL 20736        // 108*192 padded GEMM columns
#define NCHUNK 7          // K = 224 = 207 pose + 10 betas + 1 template + 6 zero
#define BT 32             // batches per k_vert block

typedef __bf16 bf16x8 __attribute__((ext_vector_type(8)));
typedef float  f32x4  __attribute__((ext_vector_type(4)));

__device__ __constant__ int c_par[24] = {-1,0,0,0,1,2,3,4,5,6,7,8,9,9,9,12,13,14,16,17,18,19,20,21};

__device__ inline unsigned short f2bf(float f) {
    unsigned u = __float_as_uint(f);
    u += 0x7fff + ((u >> 16) & 1);          // RNE
    return (unsigned short)(u >> 16);
}

__device__ inline void dma16(const void* g, void* l) {
    __builtin_amdgcn_global_load_lds(
        (const __attribute__((address_space(1))) unsigned int*)g,
        (__attribute__((address_space(3))) unsigned int*)l, 16, 0, 0);
}

// ---------------------------------------------------------------------------
// k_prep: one kernel, 4 disjoint block ranges.
//  A [0,567):      pd repack -> ws_pdt[kc][col][40] bf16 (pose;shape;template)
//  B [567,799):    pose_feature+betas+1 -> ws_pfb[b][232] bf16
//  C [799,1069):   lbs weights -> ws_wb[v][40] bf16 (v<6912)
//  D [1069,1645):  J_regressor partial reductions -> ws_jsp (8 seg x 72 x 11)
// ---------------------------------------------------------------------------
__global__ __launch_bounds__(256) void k_prep(const float* __restrict__ pd,
                                              const float* __restrict__ sd,
                                              const float* __restrict__ vtm,
                                              const float* __restrict__ Jr,
                                              const float* __restrict__ bpose,
                                              const float* __restrict__ betas,
                                              const float* __restrict__ w,
                                              unsigned short* __restrict__ ws_pdt,
                                              unsigned short* __restrict__ ws_pfb,
                                              unsigned short* __restrict__ ws_wb,
                                              float* __restrict__ ws_jsp)
{
    int blk = blockIdx.x;
    if (blk < 567) {
        int t = blk * 256 + threadIdx.x;           // 0..145151
        int kc = t / NCOL;
        int col = t - kc * NCOL;
        bool cok = col < N3;
        unsigned short vals[40];
        #pragma unroll
        for (int kk = 0; kk < 32; kk++) {
            int gk = kc * 32 + kk;
            float val = 0.f;
            if (cok) {
                if (gk < PB)             val = pd[(size_t)gk * N3 + col];
                else if (gk < PB + 10)   val = sd[(size_t)col * NBETA + (gk - PB)];
                else if (gk == PB + 10)  val = vtm[col];
            }
            vals[kk] = f2bf(val);
        }
        #pragma unroll
        for (int kk = 32; kk < 40; kk++) vals[kk] = 0;
        uint4* dst = (uint4*)(ws_pdt + (size_t)t * 40);
        #pragma unroll
        for (int q = 0; q < 5; q++) {
            uint4 u;
            u.x = vals[q*8+0] | ((unsigned)vals[q*8+1] << 16);
            u.y = vals[q*8+2] | ((unsigned)vals[q*8+3] << 16);
            u.z = vals[q*8+4] | ((unsigned)vals[q*8+5] << 16);
            u.w = vals[q*8+6] | ((unsigned)vals[q*8+7] << 16);
            dst[q] = u;
        }
    } else if (blk < 799) {
        int e0 = (blk - 567) * 1024 + threadIdx.x * 4;   // 232*1024 total
        unsigned short v4[4];
        #pragma unroll
        for (int r = 0; r < 4; r++) {
            int e = e0 + r;
            int b = e / 232, k = e - b * 232;
            float x = 0.f;
            if (k < PB) {
                x = bpose[(size_t)b * PB + k];
                int k9 = k % 9;
                if (k9 == 0 || k9 == 4 || k9 == 8) x -= 1.f;
            } else if (k < PB + 10) {
                x = betas[b * NBETA + (k - PB)];
            } else if (k == PB + 10) {
                x = 1.f;
            }
            v4[r] = f2bf(x);
        }
        uint2 u;
        u.x = v4[0] | ((unsigned)v4[1] << 16);
        u.y = v4[2] | ((unsigned)v4[3] << 16);
        *(uint2*)(ws_pfb + e0) = u;
    } else if (blk < 1069) {
        int e0 = (blk - 799) * 1024 + threadIdx.x * 4;   // 6912*40 total
        unsigned short v4[4];
        #pragma unroll
        for (int r = 0; r < 4; r++) {
            int e = e0 + r;
            int v = e / 40, j = e - v * 40;
            float val = (j < 24 && v < NV) ? w[(size_t)v * 24 + j] : 0.f;
            v4[r] = f2bf(val);
        }
        uint2 u;
        u.x = v4[0] | ((unsigned)v4[1] << 16);
        u.y = v4[2] | ((unsigned)v4[3] << 16);
        *(uint2*)(ws_wb + e0) = u;
    } else {
        int b2 = blk - 1069;           // 0..575
        int jc = b2 >> 3;              // 0..71
        int seg = b2 & 7;              // 0..7
        int j = jc / 3, c = jc % 3;
        int v0 = seg * 862;
        int v1 = v0 + 862; if (v1 > NV) v1 = NV;

        float acc[11];
        #pragma unroll
        for (int l = 0; l < 11; l++) acc[l] = 0.f;

        for (int v = v0 + threadIdx.x; v < v1; v += 256) {
            float r = Jr[j * NV + v];
            acc[10] += r * vtm[v * 3 + c];
            const float* s = sd + (size_t)(v * 3 + c) * NBETA;
            #pragma unroll
            for (int l = 0; l < NBETA; l++) acc[l] += r * s[l];
        }

        __shared__ float red[4][11];
        int lane = threadIdx.x & 63, wv = threadIdx.x >> 6;
        #pragma unroll
        for (int l = 0; l < 11; l++) {
            float x = acc[l];
            x += __shfl_down(x, 32, 64);
            x += __shfl_down(x, 16, 64);
            x += __shfl_down(x, 8, 64);
            x += __shfl_down(x, 4, 64);
            x += __shfl_down(x, 2, 64);
            x += __shfl_down(x, 1, 64);
            if (lane == 0) red[wv][l] = x;
        }
        __syncthreads();
        if (threadIdx.x == 0) {
            #pragma unroll
            for (int l = 0; l < 11; l++)
                ws_jsp[((size_t)seg * 72 + jc) * 11 + l]
                    = red[0][l] + red[1][l] + red[2][l] + red[3][l];
        }
    }
}

// ---------------------------------------------------------------------------
// k_chain: 64 blocks x 256 threads, 16 batches/block (16 lanes per batch).
// Sums js partials, joints + kinematic chain; emits bf16 ArT[b][12][40] + pj.
// ---------------------------------------------------------------------------
__global__ __launch_bounds__(256) void k_chain(const float* __restrict__ betas,
                                               const float* __restrict__ grot,
                                               const float* __restrict__ bpose,
                                               const float* __restrict__ ws_jsp,
                                               unsigned short* __restrict__ ws_artb,
                                               float* __restrict__ pj)
{
    __shared__ float js_s[72 * 11];
    __shared__ float jt[16][72];
    __shared__ float tl[16][288];
    __shared__ float am[16][288];
    int tid = threadIdx.x;

    for (int e = tid; e < 72 * 11; e += 256) {
        float s = 0.f;
        #pragma unroll
        for (int seg = 0; seg < 8; seg++)
            s += ws_jsp[(size_t)seg * 792 + e];
        js_s[e] = s;
    }
    __syncthreads();

    int lb = tid >> 4;              // 0..15
    int e  = tid & 15;              // 0..15
    int b  = blockIdx.x * 16 + lb;

    for (int idx = e; idx < 72; idx += 16) {
        float acc = js_s[idx * 11 + 10];
        const float* be = betas + b * NBETA;
        #pragma unroll
        for (int l = 0; l < NBETA; l++) acc += be[l] * js_s[idx * 11 + l];
        jt[lb][idx] = acc;
    }
    __syncthreads();

    for (int idx = e; idx < 288; idx += 16) {
        int j = idx / 12, e12 = idx % 12, m = e12 >> 2, n = e12 & 3;
        float val;
        if (n < 3) {
            val = (j == 0) ? grot[(size_t)b * 9 + m * 3 + n]
                           : bpose[((size_t)b * 23 + (j - 1)) * 9 + m * 3 + n];
        } else {
            val = jt[lb][j * 3 + m];
            if (j > 0) val -= jt[lb][c_par[j] * 3 + m];
        }
        tl[lb][idx] = val;
    }
    __syncthreads();

    if (e < 12) am[lb][e] = tl[lb][e];
    for (int i = 1; i < 24; i++) {
        __syncthreads();
        if (e < 12) {
            int p = c_par[i];
            int m = e >> 2, n = e & 3;
            float val = am[lb][p*12 + m*4 + 0] * tl[lb][i*12 + 0 + n]
                      + am[lb][p*12 + m*4 + 1] * tl[lb][i*12 + 4 + n]
                      + am[lb][p*12 + m*4 + 2] * tl[lb][i*12 + 8 + n];
            if (n == 3) val += am[lb][p*12 + m*4 + 3];
            am[lb][i*12 + e] = val;
        }
    }
    __syncthreads();

    for (int idx = e; idx < 72; idx += 16) {
        int j = idx / 3, m = idx % 3;
        pj[(size_t)b * 72 + idx] = am[lb][j*12 + m*4 + 3];
    }
    // ArT[b][col=m*4+n][j'] bf16, j' 0..39 (24..39 zero)
    for (int idx = e; idx < 480; idx += 16) {
        int col = idx / 40, j = idx - col * 40;
        float val = 0.f;
        if (j < 24) {
            int m = col >> 2, n = col & 3;
            if (n < 3) {
                val = am[lb][j*12 + col];
            } else {
                val = am[lb][j*12 + m*4 + 3]
                    - am[lb][j*12 + m*4 + 0] * jt[lb][j*3 + 0]
                    - am[lb][j*12 + m*4 + 1] * jt[lb][j*3 + 1]
                    - am[lb][j*12 + m*4 + 2] * jt[lb][j*3 + 2];
            }
        }
        ws_artb[(size_t)b * 480 + idx] = f2bf(val);
    }
}

// ---------------------------------------------------------------------------
// k_vert: phase 1 = MFMA GEMM (pf) x (pdT) -> v_posed; phase 2 = MFMA
// T = w @ ArT per 4-batch subtile + epilogue straight to out.
// All staging is global_load_lds DMA or direct global fragment loads.
// LDS 52992 B -> 3 blocks/CU. Grid (bb=32, vb=108), bb fastest for L2 reuse.
// ---------------------------------------------------------------------------
__global__ __launch_bounds__(256, 3) void k_vert(const unsigned short* __restrict__ ws_pdt,
                                                 const unsigned short* __restrict__ ws_pfb,
                                                 const unsigned short* __restrict__ ws_wb,
                                                 const unsigned short* __restrict__ ws_artb,
                                                 float* __restrict__ out)
{
    const int bb = blockIdx.x;            // 0..31
    const int vb = blockIdx.y;            // 0..107
    const int tid = threadIdx.x;
    const int wv = tid >> 6;
    const int lane = tid & 63;
    const int r16 = lane & 15;
    const int half8 = (lane >> 4) * 8;

    __shared__ __align__(16) unsigned char smem[52992];
    unsigned short* pdT_l = (unsigned short*)smem;            // [192][40] phase 1
    float*          disp_l = (float*)smem;                    // [32][196] phase 2
    unsigned short* ArT_l = (unsigned short*)(smem + 25088);  // [16*12][40]
    float*          T_l   = (float*)(smem + 40448);           // [64][49]

    // ---- DMA ArT half 0 (batches bb*32 .. +16) and pdT chunk 0
    {
        const unsigned short* srcA = ws_artb + (size_t)(bb * BT) * 480;
        for (int i = wv; i < 15; i += 4)
            dma16((const char*)srcA + i * 1024 + lane * 16, (char*)ArT_l + i * 1024);
        const unsigned short* srcP = ws_pdt + (size_t)vb * 192 * 40;
        for (int i = wv; i < 15; i += 4)
            dma16((const char*)srcP + i * 1024 + lane * 16, (char*)pdT_l + i * 1024);
    }

    const unsigned short* pfbase = ws_pfb + (size_t)(bb * BT) * 232;
    // prologue a-frags (kc=0)
    bf16x8 a0 = *(const bf16x8*)(pfbase + r16 * 232 + half8);
    bf16x8 a1 = *(const bf16x8*)(pfbase + (16 + r16) * 232 + half8);

    __syncthreads();

    f32x4 acc[2][3];
    #pragma unroll
    for (int mt = 0; mt < 2; mt++)
        #pragma unroll
        for (int t = 0; t < 3; t++)
            acc[mt][t] = (f32x4){0.f, 0.f, 0.f, 0.f};

    #pragma unroll
    for (int kc = 0; kc < NCHUNK; kc++) {
        bf16x8 b0 = *(const bf16x8*)(pdT_l + (wv * 48 + r16) * 40 + half8);
        bf16x8 b1 = *(const bf16x8*)(pdT_l + (wv * 48 + 16 + r16) * 40 + half8);
        bf16x8 b2 = *(const bf16x8*)(pdT_l + (wv * 48 + 32 + r16) * 40 + half8);
        bf16x8 a0n, a1n;
        if (kc < NCHUNK - 1) {
            a0n = *(const bf16x8*)(pfbase + r16 * 232 + (kc + 1) * 32 + half8);
            a1n = *(const bf16x8*)(pfbase + (16 + r16) * 232 + (kc + 1) * 32 + half8);
        }
        __syncthreads();                      // all frag reads of chunk kc done
        if (kc < NCHUNK - 1) {
            const unsigned short* src = ws_pdt + ((size_t)(kc + 1) * NCOL + (size_t)vb * 192) * 40;
            for (int i = wv; i < 15; i += 4)
                dma16((const char*)src + i * 1024 + lane * 16, (char*)pdT_l + i * 1024);
        }
        acc[0][0] = __builtin_amdgcn_mfma_f32_16x16x32_bf16(a0, b0, acc[0][0], 0, 0, 0);
        acc[1][0] = __builtin_amdgcn_mfma_f32_16x16x32_bf16(a1, b0, acc[1][0], 0, 0, 0);
        acc[0][1] = __builtin_amdgcn_mfma_f32_16x16x32_bf16(a0, b1, acc[0][1], 0, 0, 0);
        acc[1][1] = __builtin_amdgcn_mfma_f32_16x16x32_bf16(a1, b1, acc[1][1], 0, 0, 0);
        acc[0][2] = __builtin_amdgcn_mfma_f32_16x16x32_bf16(a0, b2, acc[0][2], 0, 0, 0);
        acc[1][2] = __builtin_amdgcn_mfma_f32_16x16x32_bf16(a1, b2, acc[1][2], 0, 0, 0);
        a0 = a0n; a1 = a1n;
        if (kc < NCHUNK - 1) __syncthreads(); // DMA(kc+1) landed
    }

    // ---- scatter v_posed into disp_l (overlays pdT; all reads done at last sync)
    #pragma unroll
    for (int mt = 0; mt < 2; mt++) {
        #pragma unroll
        for (int t = 0; t < 3; t++) {
            int col = wv * 48 + t * 16 + r16;
            int brow = mt * 16 + (lane >> 4) * 4;
            #pragma unroll
            for (int r = 0; r < 4; r++)
                disp_l[(brow + r) * 196 + col] = acc[mt][t][r];
        }
    }
    __syncthreads();

    // ---- phase 2
    bf16x8 aw = *(const bf16x8*)(ws_wb + (size_t)(vb * 64 + wv * 16 + r16) * 40 + half8);

    const int vg = vb * 64 + lane;

    for (int half = 0; half < 2; half++) {
        if (half == 1) {
            const unsigned short* srcA = ws_artb + (size_t)(bb * BT + 16) * 480;
            for (int i = wv; i < 15; i += 4)
                dma16((const char*)srcA + i * 1024 + lane * 16, (char*)ArT_l + i * 1024);
            __syncthreads();
        }
        for (int s = 0; s < 4; s++) {
            int sub = half * 4 + s;
            bf16x8 bA0 = *(const bf16x8*)(ArT_l + (s * 48 + r16) * 40 + half8);
            bf16x8 bA1 = *(const bf16x8*)(ArT_l + (s * 48 + 16 + r16) * 40 + half8);
            bf16x8 bA2 = *(const bf16x8*)(ArT_l + (s * 48 + 32 + r16) * 40 + half8);
            f32x4 z = (f32x4){0.f, 0.f, 0.f, 0.f};
            f32x4 t0 = __builtin_amdgcn_mfma_f32_16x16x32_bf16(aw, bA0, z, 0, 0, 0);
            f32x4 t1 = __builtin_amdgcn_mfma_f32_16x16x32_bf16(aw, bA1, z, 0, 0, 0);
            f32x4 t2 = __builtin_amdgcn_mfma_f32_16x16x32_bf16(aw, bA2, z, 0, 0, 0);

            int vrow = wv * 16 + (lane >> 4) * 4;
            #pragma unroll
            for (int r = 0; r < 4; r++) {
                T_l[(vrow + r) * 49 + r16]      = t0[r];
                T_l[(vrow + r) * 49 + 16 + r16] = t1[r];
                T_l[(vrow + r) * 49 + 32 + r16] = t2[r];
            }
            __syncthreads();

            if (vg < NV) {
                const float* Tv = &T_l[lane * 49 + wv * 12];
                float x = disp_l[(sub * 4 + wv) * 196 + lane * 3 + 0];
                float y = disp_l[(sub * 4 + wv) * 196 + lane * 3 + 1];
                float zz = disp_l[(sub * 4 + wv) * 196 + lane * 3 + 2];
                size_t b = (size_t)(bb * BT + sub * 4 + wv);
                float* o = out + b * N3 + (size_t)vg * 3;
                o[0] = Tv[0] * x + Tv[1] * y + Tv[2]  * zz + Tv[3];
                o[1] = Tv[4] * x + Tv[5] * y + Tv[6]  * zz + Tv[7];
                o[2] = Tv[8] * x + Tv[9] * y + Tv[10] * zz + Tv[11];
            }
            __syncthreads();
        }
    }
}

// ---------------------------------------------------------------------------
extern "C" void kernel_launch(void* const* d_in, const int* in_sizes, int n_in,
                              void* d_out, int out_size, void* d_ws, size_t ws_size,
                              hipStream_t stream) {
    const float* betas = (const float*)d_in[0];
    const float* grot  = (const float*)d_in[1];
    const float* bpose = (const float*)d_in[2];
    const float* vtm   = (const float*)d_in[3];
    const float* sd    = (const float*)d_in[4];
    const float* pd    = (const float*)d_in[5];
    const float* Jr    = (const float*)d_in[6];
    const float* w     = (const float*)d_in[7];
    float* out = (float*)d_out;

    char* ws = (char*)d_ws;
    unsigned short* ws_pdt  = (unsigned short*)(ws);              // 11,612,160 B
    unsigned short* ws_pfb  = (unsigned short*)(ws + 11612160);   //    475,136 B
    unsigned short* ws_wb   = (unsigned short*)(ws + 12087296);   //    552,960 B
    float*          ws_jsp  = (float*)         (ws + 12640256);   //     25,344 B
    unsigned short* ws_artb = (unsigned short*)(ws + 12665600);   //    983,040 B

    k_prep<<<1645, 256, 0, stream>>>(pd, sd, vtm, Jr, bpose, betas, w,
                                     ws_pdt, ws_pfb, ws_wb, ws_jsp);
    k_chain<<<BN / 16, 256, 0, stream>>>(betas, grot, bpose, ws_jsp, ws_artb,
                                         out + (size_t)BN * N3);
    k_vert<<<dim3(32, 108), 256, 0, stream>>>(ws_pdt, ws_pfb, ws_wb, ws_artb, out);
}